// Round 9
// baseline (302.339 us; speedup 1.0000x reference)
//
#include <hip/hip_runtime.h>
#include <hip/hip_bf16.h>

// B=1024, S=128, E=256, H=2, DH=128.  v/Wv/bv are dead in the reference.
// out = softmax( (q@Wq+bq)/16 |head h . (k@Wk+bk)|head h + (mask==0) ) @ Wo + bo
//
// R9: one 1024-thread block (16 waves) per batch, 128KB dynamic LDS:
//   KT[256e][128m] bf16 (64KB)  +  qp[128s][256e] bf16 (64KB, later reused
//   as P[128s][256j]).  GEMM1 reads A=weights (L2) / B=q,k rows (HBM) direct
//   from global; GEMM2 reads both operands from LDS with full K=32 MFMA;
//   3 barriers total.  16 waves/CU doubles memory-level parallelism vs R8
//   (which ran 8 waves/CU and was load-latency bound at 12% HBM).
// __launch_bounds__(1024,1): VGPR cap 128 under either blocks-per-CU or
// waves-per-EU semantics (R2/R3/R6/R7 evidence: 2nd arg behaves as blocks).
#define NB 1024
#define NS 128
#define NE 256

typedef __attribute__((ext_vector_type(8))) short bf16x8;
typedef __attribute__((ext_vector_type(4))) float f32x4;

union BF8 { bf16x8 v; unsigned u[4]; unsigned short s[8]; };

__device__ __forceinline__ unsigned short f2bf(float x) {
  unsigned u = __float_as_uint(x);
  u = (u + 0x7fffu + ((u >> 16) & 1u)) >> 16;   // RNE
  return (unsigned short)u;
}

__device__ __forceinline__ unsigned packbf(float lo, float hi) {
  return (unsigned)f2bf(lo) | ((unsigned)f2bf(hi) << 16);
}

__device__ __forceinline__ bf16x8 cvt8(float4 lo, float4 hi) {
  BF8 r;
  r.u[0] = packbf(lo.x, lo.y);
  r.u[1] = packbf(lo.z, lo.w);
  r.u[2] = packbf(hi.x, hi.y);
  r.u[3] = packbf(hi.z, hi.w);
  return r.v;
}

__device__ __forceinline__ f32x4 MF(bf16x8 a, bf16x8 b, f32x4 c) {
  return __builtin_amdgcn_mfma_f32_16x16x32_bf16(a, b, c, 0, 0, 0);
}

// WT[n][k] = W[k][n] bf16; Wq additionally prescaled by 1/16.
__global__ void prep_weights(const float* __restrict__ Wq,
                             const float* __restrict__ Wk,
                             const float* __restrict__ Wo,
                             short* __restrict__ WqT,
                             short* __restrict__ WkT,
                             short* __restrict__ WoT) {
  int idx = blockIdx.x * blockDim.x + threadIdx.x;  // = n*256 + k
  int n = idx >> 8;
  int kk = idx & 255;
  WqT[idx] = (short)f2bf(Wq[kk * NE + n] * 0.0625f);
  WkT[idx] = (short)f2bf(Wk[kk * NE + n]);
  WoT[idx] = (short)f2bf(Wo[kk * NE + n]);
}

// acc[et][ct] += proj^T tile:
//   projT[e = eg*64 + et*16 + c4*4+r][s = sg*32 + ct*16 + cl]
//     = sum_c WT[e][c] * inp[s][c]
// A = WT rows (global bf16, L2-hot, reused over ct), B = inp rows (HBM f32).
__device__ __forceinline__ void gemm_proj(const short* __restrict__ WT,
                                          const float* __restrict__ inp,
                                          int eg, int sg, int cl, int c4,
                                          f32x4 acc[4][2]) {
  #pragma unroll
  for (int ks = 0; ks < 8; ++ks) {
    bf16x8 bb[2];
    #pragma unroll
    for (int ct = 0; ct < 2; ++ct) {
      const float* rp = inp + (sg * 32 + ct * 16 + cl) * NE + ks * 32 + c4 * 8;
      bb[ct] = cvt8(*reinterpret_cast<const float4*>(rp),
                    *reinterpret_cast<const float4*>(rp + 4));
    }
    bf16x8 a[4];
    #pragma unroll
    for (int et = 0; et < 4; ++et)
      a[et] = *reinterpret_cast<const bf16x8*>(
          WT + (eg * 64 + et * 16 + cl) * NE + ks * 32 + c4 * 8);
    #pragma unroll
    for (int et = 0; et < 4; ++et)
      #pragma unroll
      for (int ct = 0; ct < 2; ++ct)
        acc[et][ct] = MF(a[et], bb[ct], acc[et][ct]);
  }
}

__global__ __launch_bounds__(1024, 1)
void fused_attn4(const float* __restrict__ q,
                 const float* __restrict__ kin,
                 const int* __restrict__ am,
                 const short* __restrict__ WqT,
                 const short* __restrict__ WkT,
                 const short* __restrict__ WoT,
                 const float* __restrict__ bq,
                 const float* __restrict__ bk,
                 const float* __restrict__ bo,
                 float* __restrict__ out) {
  extern __shared__ char LDS[];
  char* KT = LDS;            // 64KB: KT[e][m], 256 rows x 256B, swizzled
  char* QP = LDS + 65536;    // 64KB: qp[s][e], 128 rows x 512B; later P[s][j]

  const int t = threadIdx.x;
  const int lane = t & 63;
  const int wid = t >> 6;        // 16 waves
  const int cl = lane & 15;
  const int c4 = lane >> 4;
  const int b = blockIdx.x;
  const float* qb = q + (size_t)b * (NS * NE);
  const float* kb = kin + (size_t)b * (NS * NE);

  // ================= GEMM1: projections (wave grid 4x4) =================
  const int eg = wid >> 2;       // 0..3, e-range 64
  const int sg = wid & 3;        // 0..3, s/m-range 32
  {
    // GEMM1a: KT[e][m] = (k @ Wk + bk)^T
    f32x4 acc[4][2];
    #pragma unroll
    for (int et = 0; et < 4; ++et)
      #pragma unroll
      for (int ct = 0; ct < 2; ++ct) acc[et][ct] = (f32x4){0.f, 0.f, 0.f, 0.f};
    gemm_proj(WkT, kb, eg, sg, cl, c4, acc);
    #pragma unroll
    for (int et = 0; et < 4; ++et) {
      int e0 = eg * 64 + et * 16 + c4 * 4;
      float4 bk4 = *reinterpret_cast<const float4*>(bk + e0);
      #pragma unroll
      for (int ct = 0; ct < 2; ++ct) {
        int m = sg * 32 + ct * 16 + cl;
        #pragma unroll
        for (int r = 0; r < 4; ++r) {
          int e = e0 + r;
          float bv = (r == 0) ? bk4.x : (r == 1) ? bk4.y : (r == 2) ? bk4.z : bk4.w;
          *reinterpret_cast<unsigned short*>(
              KT + e * 256 + ((m * 2) ^ ((e & 7) << 4))) =
              f2bf(acc[et][ct][r] + bv);
        }
      }
    }
  }
  {
    // GEMM1b: qp[s][e] = (q @ Wq + bq) / 16   (ushort4-packed along e)
    f32x4 acc[4][2];
    #pragma unroll
    for (int et = 0; et < 4; ++et)
      #pragma unroll
      for (int ct = 0; ct < 2; ++ct) acc[et][ct] = (f32x4){0.f, 0.f, 0.f, 0.f};
    gemm_proj(WqT, qb, eg, sg, cl, c4, acc);   // WqT prescaled by 1/16
    #pragma unroll
    for (int et = 0; et < 4; ++et) {
      int e0 = eg * 64 + et * 16 + c4 * 4;
      float4 bq4 = *reinterpret_cast<const float4*>(bq + e0);
      #pragma unroll
      for (int ct = 0; ct < 2; ++ct) {
        int s = sg * 32 + ct * 16 + cl;
        uint2 w;
        w.x = packbf(acc[et][ct][0] + bq4.x * 0.0625f,
                     acc[et][ct][1] + bq4.y * 0.0625f);
        w.y = packbf(acc[et][ct][2] + bq4.z * 0.0625f,
                     acc[et][ct][3] + bq4.w * 0.0625f);
        *reinterpret_cast<uint2*>(
            QP + s * 512 + ((e0 * 2) ^ ((s & 7) << 4))) = w;
      }
    }
  }
  __syncthreads();   // KT + qp fully written

  // ===== GEMM2: scoresT[j][s] = sum_m KT[h*128+j][m] * qp[s][h*128+m] =====
  // wave = (h, sg2): h = wid>>3, s-range 16.  Full K=32 MFMA, both ops LDS.
  const int h = wid >> 3;
  const int sg2 = wid & 7;
  const int s2 = sg2 * 16 + cl;
  unsigned prpk[8][2];
  {
    f32x4 sacc[8];
    #pragma unroll
    for (int jt = 0; jt < 8; ++jt) sacc[jt] = (f32x4){0.f, 0.f, 0.f, 0.f};
    #pragma unroll
    for (int ks = 0; ks < 4; ++ks) {
      bf16x8 bv = *reinterpret_cast<const bf16x8*>(
          QP + s2 * 512 + ((h * 256 + ks * 64 + c4 * 16) ^ ((s2 & 7) << 4)));
      #pragma unroll
      for (int jt = 0; jt < 8; ++jt) {
        bf16x8 av = *reinterpret_cast<const bf16x8*>(
            KT + (h * 128 + jt * 16 + cl) * 256 +
            ((ks * 64 + c4 * 16) ^ ((cl & 7) << 4)));
        sacc[jt] = MF(av, bv, sacc[jt]);
      }
    }
    // additive mask: +1.0 where attention_mask[b][j]==0   (j axis)
    #pragma unroll
    for (int jt = 0; jt < 8; ++jt) {
      int4 mv = *reinterpret_cast<const int4*>(am + b * NS + jt * 16 + c4 * 4);
      sacc[jt][0] += (mv.x == 0) ? 1.f : 0.f;
      sacc[jt][1] += (mv.y == 0) ? 1.f : 0.f;
      sacc[jt][2] += (mv.z == 0) ? 1.f : 0.f;
      sacc[jt][3] += (mv.w == 0) ? 1.f : 0.f;
    }
    // softmax along j: 32 in-lane values then shfl_xor 16/32 (c4 groups)
    float mx = -1e30f;
    #pragma unroll
    for (int jt = 0; jt < 8; ++jt)
      #pragma unroll
      for (int r = 0; r < 4; ++r) mx = fmaxf(mx, sacc[jt][r]);
    mx = fmaxf(mx, __shfl_xor(mx, 16, 64));
    mx = fmaxf(mx, __shfl_xor(mx, 32, 64));
    float sum = 0.f;
    #pragma unroll
    for (int jt = 0; jt < 8; ++jt)
      #pragma unroll
      for (int r = 0; r < 4; ++r) {
        float ev = __expf(sacc[jt][r] - mx);
        sacc[jt][r] = ev;
        sum += ev;
      }
    sum += __shfl_xor(sum, 16, 64);
    sum += __shfl_xor(sum, 32, 64);
    float rinv = 1.0f / sum;
    #pragma unroll
    for (int jt = 0; jt < 8; ++jt) {
      prpk[jt][0] = packbf(sacc[jt][0] * rinv, sacc[jt][1] * rinv);
      prpk[jt][1] = packbf(sacc[jt][2] * rinv, sacc[jt][3] * rinv);
    }
  }
  __syncthreads();   // all qp reads complete before P overwrites the region

  // ---- P[s][j] = probs bf16 over the qp region (128 rows x 512B) ----
  #pragma unroll
  for (int jt = 0; jt < 8; ++jt) {
    *reinterpret_cast<uint2*>(
        QP + s2 * 512 + ((h * 256 + jt * 32 + c4 * 8) ^ ((s2 & 7) << 4))) =
        make_uint2(prpk[jt][0], prpk[jt][1]);
  }
  __syncthreads();

  // ---- GEMM3 (transposed): out[s][e] = sum_j Wo[j][e] * P[s][j] + bo[e]
  // A = WoT rows e (global, L2-hot), B = P rows s (LDS); float4 stores.
  {
    const int et = wid;                         // 16 e-tiles over 16 waves
    bf16x8 a[8];
    #pragma unroll
    for (int ks = 0; ks < 8; ++ks)
      a[ks] = *reinterpret_cast<const bf16x8*>(
          WoT + (et * 16 + cl) * NE + ks * 32 + c4 * 8);
    float4 bo4 = *reinterpret_cast<const float4*>(bo + et * 16 + c4 * 4);
    float* ob = out + (size_t)b * (NS * NE);
    #pragma unroll
    for (int su = 0; su < 8; ++su) {
      f32x4 acc = (f32x4){0.f, 0.f, 0.f, 0.f};
      const int row = su * 16 + cl;
      #pragma unroll
      for (int ks = 0; ks < 8; ++ks) {
        bf16x8 bv = *reinterpret_cast<const bf16x8*>(
            QP + row * 512 + ((ks * 64 + c4 * 16) ^ ((row & 7) << 4)));
        acc = MF(a[ks], bv, acc);
      }
      float4 o;
      o.x = acc[0] + bo4.x;
      o.y = acc[1] + bo4.y;
      o.z = acc[2] + bo4.z;
      o.w = acc[3] + bo4.w;
      *reinterpret_cast<float4*>(ob + row * NE + et * 16 + c4 * 4) = o;
    }
  }
}

extern "C" void kernel_launch(void* const* d_in, const int* in_sizes, int n_in,
                              void* d_out, int out_size, void* d_ws, size_t ws_size,
                              hipStream_t stream) {
  const float* q  = (const float*)d_in[0];
  const float* k  = (const float*)d_in[1];
  // d_in[2] = v : dead in the reference, never touched
  const int*   am = (const int*)d_in[3];
  const float* Wq = (const float*)d_in[4];
  const float* bq = (const float*)d_in[5];
  const float* Wk = (const float*)d_in[6];
  const float* bk = (const float*)d_in[7];
  // d_in[8] = Wv, d_in[9] = bv : dead
  const float* Wo = (const float*)d_in[10];
  const float* bo = (const float*)d_in[11];
  float* out = (float*)d_out;

  // workspace: 3 x 256x256 bf16 transposed weights = 384KB
  short* WqT = (short*)d_ws;
  short* WkT = WqT + NE * NE;
  short* WoT = WkT + NE * NE;

  prep_weights<<<NE * NE / 256, 256, 0, stream>>>(Wq, Wk, Wo, WqT, WkT, WoT);

  (void)hipFuncSetAttribute((const void*)fused_attn4,
                            hipFuncAttributeMaxDynamicSharedMemorySize, 131072);
  fused_attn4<<<NB, 1024, 131072, stream>>>(q, k, am, WqT, WkT, WoT,
                                            bq, bk, bo, out);
}